// Round 5
// baseline (55.869 us; speedup 1.0000x reference)
//
#include <hip/hip_runtime.h>
#include <cstdint>

#define HH 512
#define WW 512
#define NBATCH 16
#define NPRED 4
#define WPR 8                        // 64-bit words per row
#define NELEM (NBATCH*NPRED*HH*WW)   // 16,777,216
#define HALO 21
#define OUTR 32                      // output rows per block
#define NRTOT (OUTR + 2*HALO)        // 74 LDS data rows
#define LP 24                        // padded LDS row stride (LP%16==8: bank-friendly)
#define NBLK 1024                    // 64 slices * 16 blocks
#define NTHR 256
#define CROWS (OUTR + 8)             // 40 rows of C / H planes
#define HPL (CROWS*WPR)              // 320 words per H plane

// ---- bit-sliced helpers -----------------------------------------------------

static __device__ __forceinline__ void fadd(uint64_t a, uint64_t b, uint64_t ci,
                                            uint64_t& s, uint64_t& co) {
    uint64_t x = a ^ b;
    s  = x ^ ci;
    co = (a & b) | (ci & x);
}

static __device__ __forceinline__ void faddio(uint64_t& a, uint64_t b, uint64_t& c) {
    uint64_t x = a ^ b;
    uint64_t s = x ^ c;
    c = (a & b) | (c & x);
    a = s;
}

static __device__ __forceinline__ void sum8(const uint64_t q[8],
                                            uint64_t& b0, uint64_t& b1,
                                            uint64_t& b2, uint64_t& b3) {
    uint64_t s0,c0,s1,c1,s2,c2;
    fadd(q[0],q[1],q[2], s0,c0);
    fadd(q[3],q[4],q[5], s1,c1);
    s2 = q[6] ^ q[7]; c2 = q[6] & q[7];
    uint64_t ca; fadd(s0,s1,s2, b0, ca);
    uint64_t t, cb; fadd(c0,c1,c2, t, cb);
    b1 = t ^ ca; uint64_t cc = t & ca;
    b2 = cb ^ cc; b3 = cb & cc;
}

// w[0..6] += 4-bit number (b0..b3); max 81, no overflow past bit 6
static __device__ __forceinline__ void acc74(uint64_t w[7], uint64_t b0, uint64_t b1,
                                             uint64_t b2, uint64_t b3) {
    uint64_t c;
    { uint64_t x = w[0] ^ b0; c = w[0] & b0; w[0] = x; }
    faddio(w[1], b1, c);
    faddio(w[2], b2, c);
    faddio(w[3], b3, c);
    { uint64_t x = w[4] ^ c; c = w[4] & c; w[4] = x; }
    { uint64_t x = w[5] ^ c; c = w[5] & c; w[5] = x; }
    w[6] ^= c;
}

// ---- kernels ----------------------------------------------------------------

// softmax over batch axis (float4-vectorized), threshold 0.5, pack bits.
__global__ __launch_bounds__(256) void k_binarize(const float* __restrict__ x,
                                                  uint64_t* __restrict__ pack,
                                                  unsigned int* __restrict__ cnt) {
    if (blockIdx.x == 0 && threadIdx.x == 0) *cnt = 0u;   // reset last-block counter
    __shared__ uint64_t nibs[272];                        // 256 + per-16 pad
    const int t = blockIdx.x * 256 + threadIdx.x;         // float4 index in (p,h,w)
    const float4* __restrict__ xv = reinterpret_cast<const float4*>(x);
    float4 va[NBATCH];
    #pragma unroll
    for (int b = 0; b < NBATCH; ++b) va[b] = xv[(size_t)b * (NPRED*HH*WW/4) + t];
    float4 mx = va[0];
    #pragma unroll
    for (int b = 1; b < NBATCH; ++b) {
        mx.x = fmaxf(mx.x, va[b].x); mx.y = fmaxf(mx.y, va[b].y);
        mx.z = fmaxf(mx.z, va[b].z); mx.w = fmaxf(mx.w, va[b].w);
    }
    float sx=0.f, sy=0.f, sz=0.f, sw=0.f;
    #pragma unroll
    for (int b = 0; b < NBATCH; ++b) {
        sx += __expf(va[b].x - mx.x); sy += __expf(va[b].y - mx.y);
        sz += __expf(va[b].z - mx.z); sw += __expf(va[b].w - mx.w);
    }
    const float tx = mx.x + __logf(0.5f*sx), ty = mx.y + __logf(0.5f*sy);
    const float tz = mx.z + __logf(0.5f*sz), tw = mx.w + __logf(0.5f*sw);
    uint64_t nib = 0;
    #pragma unroll
    for (int b = 0; b < NBATCH; ++b) {
        unsigned n = (va[b].x >= tx ? 1u:0u) | (va[b].y >= ty ? 2u:0u)
                   | (va[b].z >= tz ? 4u:0u) | (va[b].w >= tw ? 8u:0u);
        nib |= (uint64_t)n << (4*b);
    }
    nibs[threadIdx.x + (threadIdx.x >> 4)] = nib;
    __syncthreads();
    // assemble one 64-px word per (wg,b) pair
    const int wg = threadIdx.x >> 4, b = threadIdx.x & 15;
    uint64_t word = 0;
    #pragma unroll
    for (int j = 0; j < 16; ++j)
        word |= ((nibs[wg*17 + j] >> (4*b)) & 0xFULL) << (4*j);
    const int wgg = blockIdx.x * 16 + wg;                 // global word index
    const int wword = wgg & 7;
    const int h = (wgg >> 3) & (HH-1);
    const int p = wgg >> 12;
    pack[((size_t)(b*NPRED + p)*HH + h)*WPR + wword] = word;
}

// fused: <=16 Zhang-Suen substeps (cone-shrunk + early-exit) + endpoint C +
// 9x9-minus-center weight + sparse loss eval + last-block global reduction.
__global__ __launch_bounds__(NTHR) void k_thin_wmap(const uint64_t* __restrict__ pack,
                                                    const float* __restrict__ x,
                                                    const float* __restrict__ y,
                                                    double* __restrict__ partials,
                                                    unsigned int* __restrict__ cnt,
                                                    float* __restrict__ out) {
    __shared__ uint64_t A[(NRTOT+2)*LP];
    __shared__ uint64_t B[(NRTOT+2)*LP];
    __shared__ double sdata[NTHR];
    __shared__ int chg[16];
    __shared__ int cflag;
    __shared__ int lastFlag;

    const int s    = blockIdx.x >> 4;
    const int base = (blockIdx.x & 15) << 5;   // 32 rows per block
    const int R0   = base - HALO;
    const int tid  = threadIdx.x;

    for (int i = tid; i < (NRTOT+2)*LP; i += NTHR) { A[i] = 0; B[i] = 0; }
    if (tid < 16) chg[tid] = 0;
    if (tid == 0) cflag = 0;
    __syncthreads();
    for (int i = tid; i < NRTOT*WPR; i += NTHR) {
        int lr = i >> 3, c = i & 7;
        int r = R0 + lr;
        if ((unsigned)r < (unsigned)HH)
            A[(lr+1)*LP + c + 1] = pack[((size_t)s*HH + r)*WPR + c];
    }
    __syncthreads();

    uint64_t* cur = A; uint64_t* nxt = B;
    int stable = 0;
    for (int step = 0; step < 16 && stable < 2; ++step) {
        const int lo = step + 1;
        const int nw = (NRTOT - 2 - 2*step) * WPR;        // rows [lo, 73-step)
        bool mych = false;
        for (int i = tid; i < nw; i += NTHR) {
            const int lr = (i >> 3) + lo;
            const int c = i & 7;
            const int o = (lr+1)*LP + c + 1;
            uint64_t up = cur[o-LP-1], uc = cur[o-LP], un = cur[o-LP+1];
            uint64_t mp = cur[o-1],    mc = cur[o],    mn = cur[o+1];
            uint64_t dp = cur[o+LP-1], dc = cur[o+LP], dn = cur[o+LP+1];
            uint64_t p2 = uc;
            uint64_t p3 = (uc>>1)|(un<<63);
            uint64_t p4 = (mc>>1)|(mn<<63);
            uint64_t p5 = (dc>>1)|(dn<<63);
            uint64_t p6 = dc;
            uint64_t p7 = (dc<<1)|(dp>>63);
            uint64_t p8 = (mc<<1)|(mp>>63);
            uint64_t p9 = (uc<<1)|(up>>63);
            uint64_t qq[8] = {p2,p3,p4,p5,p6,p7,p8,p9};
            uint64_t n0,n1,n2,n3; sum8(qq,n0,n1,n2,n3);
            uint64_t condB = (n1|n2|n3) & ~(n3 | (n2&n1&n0));
            uint64_t tq[8];
            #pragma unroll
            for (int k = 0; k < 8; ++k) tq[k] = ~qq[k] & qq[(k+1)&7];
            uint64_t t0,t1,t2,t3; sum8(tq,t0,t1,t2,t3);
            uint64_t trans1 = t0 & ~(t1|t2|t3);
            uint64_t cond2 = (step & 1) ? (~(p2&p4&p8) & ~(p2&p6&p8))
                                        : (~(p2&p4&p6) & ~(p4&p6&p8));
            uint64_t nv = mc & ~(condB & trans1 & cond2);
            nxt[o] = nv;
            mych |= (nv != mc);
        }
        if (mych) chg[step] = 1;
        __syncthreads();
        stable = chg[step] ? 0 : stable + 1;
        uint64_t* tmp = cur; cur = nxt; nxt = tmp;
    }

    // Endpoint C from skeleton (cur) into Cb (nxt), rows lr in [17, 57).
    uint64_t* Cb = nxt;
    for (int i = tid; i < CROWS*WPR; i += NTHR) {
        const int lr = (i >> 3) + (HALO - 4);
        const int c = i & 7;
        const int o = (lr+1)*LP + c + 1;
        uint64_t up = cur[o-LP-1], uc = cur[o-LP], un = cur[o-LP+1];
        uint64_t mp = cur[o-1],    mc = cur[o],    mn = cur[o+1];
        uint64_t dp = cur[o+LP-1], dc = cur[o+LP], dn = cur[o+LP+1];
        uint64_t p3 = (uc>>1)|(un<<63);
        uint64_t p4 = (mc>>1)|(mn<<63);
        uint64_t p5 = (dc>>1)|(dn<<63);
        uint64_t p7 = (dc<<1)|(dp>>63);
        uint64_t p8 = (mc<<1)|(mp>>63);
        uint64_t p9 = (uc<<1)|(up>>63);
        uint64_t cv = uc & p3 & p4 & p5 & dc & p7 & p8 & p9;
        Cb[o] = cv;
        if (cv) cflag = 1;
    }
    __syncthreads();

    double acc = 0.0;
    if (cflag) {
        // Phase A: horizontal 9-window sums -> 4 bit-planes, overlaid on dead skeleton
        uint64_t* Hp = cur;
        for (int i = tid; i < CROWS*WPR; i += NTHR) {
            const int hr = i >> 3, c = i & 7;
            const int o = (hr + HALO - 3)*LP + c + 1;  // lr = hr+17, +1 pad row
            uint64_t mp = Cb[o-1], mc = Cb[o], mn = Cb[o+1];
            uint64_t m[8];
            m[0] = (mc>>1)|(mn<<63); m[1] = (mc>>2)|(mn<<62);
            m[2] = (mc>>3)|(mn<<61); m[3] = (mc>>4)|(mn<<60);
            m[4] = (mc<<1)|(mp>>63); m[5] = (mc<<2)|(mp>>62);
            m[6] = (mc<<3)|(mp>>61); m[7] = (mc<<4)|(mp>>60);
            uint64_t b0,b1,b2,b3; sum8(m,b0,b1,b2,b3);
            uint64_t inc = mc;
            uint64_t s0 = b0 ^ inc; inc &= b0;
            uint64_t s1 = b1 ^ inc; inc &= b1;
            uint64_t s2 = b2 ^ inc; inc &= b2;
            uint64_t s3 = b3 ^ inc;
            Hp[0*HPL + i] = s0; Hp[1*HPL + i] = s1;
            Hp[2*HPL + i] = s2; Hp[3*HPL + i] = s3;
        }
        __syncthreads();
        // Phase B: vertical 9-row sums -> 7-bit weight, minus center C, sparse eval.
        {
            const int i = tid;                         // 256 threads == OUTR*WPR words
            const int orr = i >> 3, c = i & 7;
            uint64_t w[7];
            const int h0 = orr*WPR + c;
            w[0] = Hp[h0]; w[1] = Hp[HPL + h0]; w[2] = Hp[2*HPL + h0]; w[3] = Hp[3*HPL + h0];
            w[4] = 0; w[5] = 0; w[6] = 0;
            #pragma unroll
            for (int d = 1; d < 9; ++d) {
                const int hh = (orr+d)*WPR + c;
                acc74(w, Hp[hh], Hp[HPL+hh], Hp[2*HPL+hh], Hp[3*HPL+hh]);
            }
            uint64_t cb = Cb[(orr + HALO + 1)*LP + c + 1];
            #pragma unroll
            for (int j = 0; j < 7; ++j) {
                uint64_t t = w[j];
                w[j] = t ^ cb;
                cb &= ~t;
            }
            uint64_t any = w[0]|w[1]|w[2]|w[3]|w[4]|w[5]|w[6];
            if (any) {
                size_t pix0 = ((size_t)s*HH + (base + orr))*WW + ((size_t)c << 6);
                uint64_t rem = any;
                while (rem) {
                    int bit = __builtin_ctzll(rem);
                    rem &= rem - 1;
                    int wv = 0;
                    #pragma unroll
                    for (int j = 0; j < 7; ++j) wv |= (int)((w[j] >> bit) & 1ULL) << j;
                    size_t idx = pix0 + bit;
                    float lx = x[idx], ly = y[idx];
                    float loss = fmaxf(lx, 0.f) - lx*ly + log1pf(expf(-fabsf(lx)));
                    acc += (double)(loss * (60.0f * (float)wv));
                }
            }
        }
    }

    // block tree-reduce
    sdata[tid] = acc;
    __syncthreads();
    for (int s2 = NTHR/2; s2 > 0; s2 >>= 1) {
        if (tid < s2) sdata[tid] += sdata[tid + s2];
        __syncthreads();
    }
    if (tid == 0) {
        __hip_atomic_store(&partials[blockIdx.x], sdata[0],
                           __ATOMIC_RELEASE, __HIP_MEMORY_SCOPE_AGENT);
        unsigned old = __hip_atomic_fetch_add(cnt, 1u,
                           __ATOMIC_ACQ_REL, __HIP_MEMORY_SCOPE_AGENT);
        lastFlag = (old == NBLK - 1);
    }
    __syncthreads();
    if (!lastFlag) return;

    // last block: deterministic fixed-order global reduction
    double a = 0.0;
    for (int i = tid; i < NBLK; i += NTHR)
        a += __hip_atomic_load(&partials[i], __ATOMIC_RELAXED, __HIP_MEMORY_SCOPE_AGENT);
    sdata[tid] = a;
    __syncthreads();
    for (int s2 = NTHR/2; s2 > 0; s2 >>= 1) {
        if (tid < s2) sdata[tid] += sdata[tid + s2];
        __syncthreads();
    }
    if (tid == 0) {
        out[0] = (float)(sdata[0] / (double)NELEM);
        __hip_atomic_store(cnt, 0u, __ATOMIC_RELAXED, __HIP_MEMORY_SCOPE_AGENT);
    }
}

// ---- launch ------------------------------------------------------------------

extern "C" void kernel_launch(void* const* d_in, const int* in_sizes, int n_in,
                              void* d_out, int out_size, void* d_ws, size_t ws_size,
                              hipStream_t stream) {
    const float* x = (const float*)d_in[0];
    const float* y = (const float*)d_in[1];
    char* ws = (char*)d_ws;
    double*       partials = (double*)(ws);                 // 8 KB
    unsigned int* cnt      = (unsigned int*)(ws + 8192);    // 4 B
    uint64_t*     packA    = (uint64_t*)(ws + 16384);       // 2 MB

    k_binarize<<<1024, 256, 0, stream>>>(x, packA, cnt);
    k_thin_wmap<<<NBLK, NTHR, 0, stream>>>(packA, x, y, partials, cnt, (float*)d_out);
}

// Round 6
// 31.148 us; speedup vs baseline: 1.7937x; 1.7937x over previous
//
#include <hip/hip_runtime.h>
#include <cstdint>

#define HH 512
#define WW 512
#define NBATCH 16
#define NPRED 4
#define WPR 8                        // 64-bit words per row
#define NELEM (NBATCH*NPRED*HH*WW)   // 16,777,216
#define HALO 21
#define OUTR 64                      // output rows per block
#define NRTOT (OUTR + 2*HALO)        // 106 LDS data rows
#define LP (WPR+2)                   // padded LDS row stride (=10: spreads banks)
#define NBLK 512                     // 64 slices * 8 blocks
#define NTHR 256

// ---- bit-sliced helpers -----------------------------------------------------

static __device__ __forceinline__ void fadd(uint64_t a, uint64_t b, uint64_t ci,
                                            uint64_t& s, uint64_t& co) {
    uint64_t x = a ^ b;
    s  = x ^ ci;
    co = (a & b) | (ci & x);
}

static __device__ __forceinline__ void faddio(uint64_t& a, uint64_t b, uint64_t& c) {
    uint64_t x = a ^ b;
    uint64_t s = x ^ c;
    c = (a & b) | (c & x);
    a = s;
}

static __device__ __forceinline__ void sum8(const uint64_t q[8],
                                            uint64_t& b0, uint64_t& b1,
                                            uint64_t& b2, uint64_t& b3) {
    uint64_t s0,c0,s1,c1,s2,c2;
    fadd(q[0],q[1],q[2], s0,c0);
    fadd(q[3],q[4],q[5], s1,c1);
    s2 = q[6] ^ q[7]; c2 = q[6] & q[7];
    uint64_t ca; fadd(s0,s1,s2, b0, ca);
    uint64_t t, cb; fadd(c0,c1,c2, t, cb);
    b1 = t ^ ca; uint64_t cc = t & ca;
    b2 = cb ^ cc; b3 = cb & cc;
}

// w[0..6] += 4-bit number (b0..b3); max 81, no overflow past bit 6
static __device__ __forceinline__ void acc74(uint64_t w[7], uint64_t b0, uint64_t b1,
                                             uint64_t b2, uint64_t b3) {
    uint64_t c;
    { uint64_t x = w[0] ^ b0; c = w[0] & b0; w[0] = x; }
    faddio(w[1], b1, c);
    faddio(w[2], b2, c);
    faddio(w[3], b3, c);
    { uint64_t x = w[4] ^ c; c = w[4] & c; w[4] = x; }
    { uint64_t x = w[5] ^ c; c = w[5] & c; w[5] = x; }
    w[6] ^= c;
}

// ---- kernels ----------------------------------------------------------------

// softmax over batch axis (float4-vectorized), threshold 0.5, pack bits.
__global__ __launch_bounds__(256) void k_binarize(const float* __restrict__ x,
                                                  uint64_t* __restrict__ pack) {
    __shared__ uint64_t nibs[272];                        // 256 + per-16 pad
    const int t = blockIdx.x * 256 + threadIdx.x;         // float4 index in (p,h,w)
    const float4* __restrict__ xv = reinterpret_cast<const float4*>(x);
    float4 va[NBATCH];
    #pragma unroll
    for (int b = 0; b < NBATCH; ++b) va[b] = xv[(size_t)b * (NPRED*HH*WW/4) + t];
    float4 mx = va[0];
    #pragma unroll
    for (int b = 1; b < NBATCH; ++b) {
        mx.x = fmaxf(mx.x, va[b].x); mx.y = fmaxf(mx.y, va[b].y);
        mx.z = fmaxf(mx.z, va[b].z); mx.w = fmaxf(mx.w, va[b].w);
    }
    float sx=0.f, sy=0.f, sz=0.f, sw=0.f;
    #pragma unroll
    for (int b = 0; b < NBATCH; ++b) {
        sx += __expf(va[b].x - mx.x); sy += __expf(va[b].y - mx.y);
        sz += __expf(va[b].z - mx.z); sw += __expf(va[b].w - mx.w);
    }
    const float tx = mx.x + __logf(0.5f*sx), ty = mx.y + __logf(0.5f*sy);
    const float tz = mx.z + __logf(0.5f*sz), tw = mx.w + __logf(0.5f*sw);
    uint64_t nib = 0;
    #pragma unroll
    for (int b = 0; b < NBATCH; ++b) {
        unsigned n = (va[b].x >= tx ? 1u:0u) | (va[b].y >= ty ? 2u:0u)
                   | (va[b].z >= tz ? 4u:0u) | (va[b].w >= tw ? 8u:0u);
        nib |= (uint64_t)n << (4*b);
    }
    nibs[threadIdx.x + (threadIdx.x >> 4)] = nib;
    __syncthreads();
    // assemble one 64-px word per (wg,b) pair
    const int wg = threadIdx.x >> 4, b = threadIdx.x & 15;
    uint64_t word = 0;
    #pragma unroll
    for (int j = 0; j < 16; ++j)
        word |= ((nibs[wg*17 + j] >> (4*b)) & 0xFULL) << (4*j);
    const int wgg = blockIdx.x * 16 + wg;                 // global word index
    const int wword = wgg & 7;
    const int h = (wgg >> 3) & (HH-1);
    const int p = wgg >> 12;
    pack[((size_t)(b*NPRED + p)*HH + h)*WPR + wword] = word;
}

// fused: 16 Zhang-Suen substeps (early-exit on convergence) + endpoint C +
// 9x9-minus-center weight + sparse loss evaluation -> per-block double partial.
__global__ __launch_bounds__(NTHR) void k_thin_wmap(const uint64_t* __restrict__ pack,
                                                    const float* __restrict__ x,
                                                    const float* __restrict__ y,
                                                    double* __restrict__ partials) {
    __shared__ uint64_t A[(NRTOT+2)*LP];
    __shared__ uint64_t B[(NRTOT+2)*LP];
    __shared__ uint64_t Hs[4*72*WPR];                  // horizontal-sum planes
    __shared__ int chg[16];
    __shared__ int cflag;
    __shared__ double sdata[NTHR];

    const int s    = blockIdx.x >> 3;
    const int base = (blockIdx.x & 7) << 6;
    const int R0   = base - HALO;
    const int tid  = threadIdx.x;

    for (int i = tid; i < (NRTOT+2)*LP; i += NTHR) { A[i] = 0; B[i] = 0; }
    if (tid < 16) chg[tid] = 0;
    if (tid == 0) cflag = 0;
    __syncthreads();
    for (int i = tid; i < NRTOT*WPR; i += NTHR) {
        int lr = i >> 3, c = i & 7;
        int r = R0 + lr;
        if ((unsigned)r < (unsigned)HH)
            A[(lr+1)*LP + c + 1] = pack[((size_t)s*HH + r)*WPR + c];
    }
    __syncthreads();

    uint64_t* cur = A; uint64_t* nxt = B;
    int stable = 0;
    for (int step = 0; step < 16; ++step) {
        if (stable >= 2) break;                        // uniform across block
        bool mych = false;
        for (int i = tid; i < NRTOT*WPR; i += NTHR) {
            int lr = i >> 3, c = i & 7;
            int o = (lr+1)*LP + c + 1;
            uint64_t up = cur[o-LP-1], uc = cur[o-LP], un = cur[o-LP+1];
            uint64_t mp = cur[o-1],    mc = cur[o],    mn = cur[o+1];
            uint64_t dp = cur[o+LP-1], dc = cur[o+LP], dn = cur[o+LP+1];
            uint64_t p2 = uc;
            uint64_t p3 = (uc>>1)|(un<<63);
            uint64_t p4 = (mc>>1)|(mn<<63);
            uint64_t p5 = (dc>>1)|(dn<<63);
            uint64_t p6 = dc;
            uint64_t p7 = (dc<<1)|(dp>>63);
            uint64_t p8 = (mc<<1)|(mp>>63);
            uint64_t p9 = (uc<<1)|(up>>63);
            uint64_t qq[8] = {p2,p3,p4,p5,p6,p7,p8,p9};
            uint64_t n0,n1,n2,n3; sum8(qq,n0,n1,n2,n3);
            uint64_t condB = (n1|n2|n3) & ~(n3 | (n2&n1&n0));
            uint64_t tq[8];
            #pragma unroll
            for (int k = 0; k < 8; ++k) tq[k] = ~qq[k] & qq[(k+1)&7];
            uint64_t t0,t1,t2,t3; sum8(tq,t0,t1,t2,t3);
            uint64_t trans1 = t0 & ~(t1|t2|t3);
            uint64_t cond2 = (step & 1) ? (~(p2&p4&p8) & ~(p2&p6&p8))
                                        : (~(p2&p4&p6) & ~(p4&p6&p8));
            uint64_t nv = mc & ~(condB & trans1 & cond2);
            nxt[o] = nv;
            mych |= (nv != mc);
        }
        if (mych) chg[step] = 1;
        __syncthreads();
        stable = chg[step] ? 0 : stable + 1;
        uint64_t* t = cur; cur = nxt; nxt = t;
    }

    // Endpoint C (all 8 neighbors set) from skeleton (cur) into Cb (nxt),
    // rows lr 17..88.
    uint64_t* Cb = nxt;
    for (int i = tid; i < 72*WPR; i += NTHR) {
        int lr = (i >> 3) + 17, c = i & 7;
        int o = (lr+1)*LP + c + 1;
        uint64_t up = cur[o-LP-1], uc = cur[o-LP], un = cur[o-LP+1];
        uint64_t mp = cur[o-1],    mc = cur[o],    mn = cur[o+1];
        uint64_t dp = cur[o+LP-1], dc = cur[o+LP], dn = cur[o+LP+1];
        uint64_t p3 = (uc>>1)|(un<<63);
        uint64_t p4 = (mc>>1)|(mn<<63);
        uint64_t p5 = (dc>>1)|(dn<<63);
        uint64_t p7 = (dc<<1)|(dp>>63);
        uint64_t p8 = (mc<<1)|(mp>>63);
        uint64_t p9 = (uc<<1)|(up>>63);
        uint64_t cv = uc & p3 & p4 & p5 & dc & p7 & p8 & p9;
        Cb[o] = cv;
        if (cv) cflag = 1;
    }
    __syncthreads();

    if (!cflag) {                                      // uniform: weight map is 0
        if (tid == 0) partials[blockIdx.x] = 0.0;
        return;
    }

    // Phase A: horizontal 9-window sums (center included) -> 4 bit-planes
    for (int i = tid; i < 72*WPR; i += NTHR) {
        int hr = i >> 3, c = i & 7;
        int o = (hr+18)*LP + c + 1;                    // lr = hr+17
        uint64_t mp = Cb[o-1], mc = Cb[o], mn = Cb[o+1];
        uint64_t m[8];
        m[0] = (mc>>1)|(mn<<63); m[1] = (mc>>2)|(mn<<62);
        m[2] = (mc>>3)|(mn<<61); m[3] = (mc>>4)|(mn<<60);
        m[4] = (mc<<1)|(mp>>63); m[5] = (mc<<2)|(mp>>62);
        m[6] = (mc<<3)|(mp>>61); m[7] = (mc<<4)|(mp>>60);
        uint64_t b0,b1,b2,b3; sum8(m,b0,b1,b2,b3);
        uint64_t inc = mc;
        uint64_t s0 = b0 ^ inc; inc &= b0;
        uint64_t s1 = b1 ^ inc; inc &= b1;
        uint64_t s2 = b2 ^ inc; inc &= b2;
        uint64_t s3 = b3 ^ inc;
        Hs[0*576 + i] = s0; Hs[1*576 + i] = s1;
        Hs[2*576 + i] = s2; Hs[3*576 + i] = s3;
    }
    __syncthreads();

    // Phase B: vertical 9-row sums -> 7-bit weight, minus center C bit,
    // then sparse loss evaluation.
    double acc = 0.0;
    for (int i = tid; i < OUTR*WPR; i += NTHR) {
        int orr = i >> 3, c = i & 7;
        uint64_t w[7];
        int h0 = orr*WPR + c;
        w[0] = Hs[0*576 + h0]; w[1] = Hs[1*576 + h0];
        w[2] = Hs[2*576 + h0]; w[3] = Hs[3*576 + h0];
        w[4] = 0; w[5] = 0; w[6] = 0;
        #pragma unroll
        for (int d = 1; d < 9; ++d) {
            int hh = (orr+d)*WPR + c;
            acc74(w, Hs[0*576+hh], Hs[1*576+hh], Hs[2*576+hh], Hs[3*576+hh]);
        }
        uint64_t cb = Cb[(orr+HALO+1)*LP + c + 1];
        #pragma unroll
        for (int j = 0; j < 7; ++j) {
            uint64_t t = w[j];
            w[j] = t ^ cb;
            cb &= ~t;
        }
        uint64_t any = w[0]|w[1]|w[2]|w[3]|w[4]|w[5]|w[6];
        if (any) {
            size_t pix0 = ((size_t)s*HH + (base + orr))*WW + ((size_t)c << 6);
            uint64_t rem = any;
            while (rem) {
                int bit = __builtin_ctzll(rem);
                rem &= rem - 1;
                int wv = 0;
                #pragma unroll
                for (int j = 0; j < 7; ++j) wv |= (int)((w[j] >> bit) & 1ULL) << j;
                size_t idx = pix0 + bit;
                float lx = x[idx], ly = y[idx];
                float loss = fmaxf(lx, 0.f) - lx*ly + log1pf(expf(-fabsf(lx)));
                acc += (double)(loss * (60.0f * (float)wv));
            }
        }
    }
    sdata[tid] = acc;
    __syncthreads();
    for (int s2 = NTHR/2; s2 > 0; s2 >>= 1) {
        if (tid < s2) sdata[tid] += sdata[tid + s2];
        __syncthreads();
    }
    if (tid == 0) partials[blockIdx.x] = sdata[0];
}

__global__ void k_reduce(const double* __restrict__ partials, float* __restrict__ out,
                         int nparts) {
    __shared__ double sdata[256];
    double a = 0.0;
    for (int i = threadIdx.x; i < nparts; i += 256) a += partials[i];
    sdata[threadIdx.x] = a;
    __syncthreads();
    for (int s2 = 128; s2 > 0; s2 >>= 1) {
        if (threadIdx.x < s2) sdata[threadIdx.x] += sdata[threadIdx.x + s2];
        __syncthreads();
    }
    if (threadIdx.x == 0) out[0] = (float)(sdata[0] / (double)NELEM);
}

// ---- launch ------------------------------------------------------------------

extern "C" void kernel_launch(void* const* d_in, const int* in_sizes, int n_in,
                              void* d_out, int out_size, void* d_ws, size_t ws_size,
                              hipStream_t stream) {
    const float* x = (const float*)d_in[0];
    const float* y = (const float*)d_in[1];
    char* ws = (char*)d_ws;
    double*   partials = (double*)(ws);                 // 4 KB
    uint64_t* packA    = (uint64_t*)(ws + 16384);       // 2 MB

    k_binarize<<<1024, 256, 0, stream>>>(x, packA);
    k_thin_wmap<<<NBLK, NTHR, 0, stream>>>(packA, x, y, partials);
    k_reduce<<<1, 256, 0, stream>>>(partials, (float*)d_out, NBLK);
}

// Round 7
// 29.752 us; speedup vs baseline: 1.8779x; 1.0469x over previous
//
#include <hip/hip_runtime.h>
#include <cstdint>

#define HH 512
#define WW 512
#define NBATCH 16
#define NPRED 4
#define WPR 8                        // 64-bit words per row
#define NELEM (NBATCH*NPRED*HH*WW)   // 16,777,216
#define HALO 21
#define OUTR 64                      // output rows per block
#define NRTOT (OUTR + 2*HALO)        // 106 LDS data rows
#define LP (WPR+2)                   // padded LDS row stride (=10: spreads banks)
#define NBLK 512                     // 64 slices * 8 blocks
#define NTHR 512                     // 8 waves/block -> 16 waves/CU at 2 blocks/CU

// ---- bit-sliced helpers -----------------------------------------------------

static __device__ __forceinline__ void fadd(uint64_t a, uint64_t b, uint64_t ci,
                                            uint64_t& s, uint64_t& co) {
    uint64_t x = a ^ b;
    s  = x ^ ci;
    co = (a & b) | (ci & x);
}

static __device__ __forceinline__ void faddio(uint64_t& a, uint64_t b, uint64_t& c) {
    uint64_t x = a ^ b;
    uint64_t s = x ^ c;
    c = (a & b) | (c & x);
    a = s;
}

static __device__ __forceinline__ void sum8(const uint64_t q[8],
                                            uint64_t& b0, uint64_t& b1,
                                            uint64_t& b2, uint64_t& b3) {
    uint64_t s0,c0,s1,c1,s2,c2;
    fadd(q[0],q[1],q[2], s0,c0);
    fadd(q[3],q[4],q[5], s1,c1);
    s2 = q[6] ^ q[7]; c2 = q[6] & q[7];
    uint64_t ca; fadd(s0,s1,s2, b0, ca);
    uint64_t t, cb; fadd(c0,c1,c2, t, cb);
    b1 = t ^ ca; uint64_t cc = t & ca;
    b2 = cb ^ cc; b3 = cb & cc;
}

// w[0..6] += 4-bit number (b0..b3); max 81, no overflow past bit 6
static __device__ __forceinline__ void acc74(uint64_t w[7], uint64_t b0, uint64_t b1,
                                             uint64_t b2, uint64_t b3) {
    uint64_t c;
    { uint64_t x = w[0] ^ b0; c = w[0] & b0; w[0] = x; }
    faddio(w[1], b1, c);
    faddio(w[2], b2, c);
    faddio(w[3], b3, c);
    { uint64_t x = w[4] ^ c; c = w[4] & c; w[4] = x; }
    { uint64_t x = w[5] ^ c; c = w[5] & c; w[5] = x; }
    w[6] ^= c;
}

// ---- kernels ----------------------------------------------------------------

// softmax over batch axis (float4-vectorized), threshold 0.5, pack bits.
__global__ __launch_bounds__(256) void k_binarize(const float* __restrict__ x,
                                                  uint64_t* __restrict__ pack) {
    __shared__ uint64_t nibs[272];                        // 256 + per-16 pad
    const int t = blockIdx.x * 256 + threadIdx.x;         // float4 index in (p,h,w)
    const float4* __restrict__ xv = reinterpret_cast<const float4*>(x);
    float4 va[NBATCH];
    #pragma unroll
    for (int b = 0; b < NBATCH; ++b) va[b] = xv[(size_t)b * (NPRED*HH*WW/4) + t];
    float4 mx = va[0];
    #pragma unroll
    for (int b = 1; b < NBATCH; ++b) {
        mx.x = fmaxf(mx.x, va[b].x); mx.y = fmaxf(mx.y, va[b].y);
        mx.z = fmaxf(mx.z, va[b].z); mx.w = fmaxf(mx.w, va[b].w);
    }
    float sx=0.f, sy=0.f, sz=0.f, sw=0.f;
    #pragma unroll
    for (int b = 0; b < NBATCH; ++b) {
        sx += __expf(va[b].x - mx.x); sy += __expf(va[b].y - mx.y);
        sz += __expf(va[b].z - mx.z); sw += __expf(va[b].w - mx.w);
    }
    const float tx = mx.x + __logf(0.5f*sx), ty = mx.y + __logf(0.5f*sy);
    const float tz = mx.z + __logf(0.5f*sz), tw = mx.w + __logf(0.5f*sw);
    uint64_t nib = 0;
    #pragma unroll
    for (int b = 0; b < NBATCH; ++b) {
        unsigned n = (va[b].x >= tx ? 1u:0u) | (va[b].y >= ty ? 2u:0u)
                   | (va[b].z >= tz ? 4u:0u) | (va[b].w >= tw ? 8u:0u);
        nib |= (uint64_t)n << (4*b);
    }
    nibs[threadIdx.x + (threadIdx.x >> 4)] = nib;
    __syncthreads();
    // assemble one 64-px word per (wg,b) pair
    const int wg = threadIdx.x >> 4, b = threadIdx.x & 15;
    uint64_t word = 0;
    #pragma unroll
    for (int j = 0; j < 16; ++j)
        word |= ((nibs[wg*17 + j] >> (4*b)) & 0xFULL) << (4*j);
    const int wgg = blockIdx.x * 16 + wg;                 // global word index
    const int wword = wgg & 7;
    const int h = (wgg >> 3) & (HH-1);
    const int p = wgg >> 12;
    pack[((size_t)(b*NPRED + p)*HH + h)*WPR + wword] = word;
}

// fused: 16 Zhang-Suen substeps (cone-shrunk + early-exit) + endpoint C +
// 9x9-minus-center weight + sparse loss evaluation -> per-block double partial.
__global__ __launch_bounds__(NTHR) void k_thin_wmap(const uint64_t* __restrict__ pack,
                                                    const float* __restrict__ x,
                                                    const float* __restrict__ y,
                                                    double* __restrict__ partials) {
    __shared__ uint64_t A[(NRTOT+2)*LP];
    __shared__ uint64_t B[(NRTOT+2)*LP];
    __shared__ uint64_t Hs[4*72*WPR];                  // horizontal-sum planes
    __shared__ int chg[16];
    __shared__ int cflag;
    __shared__ double sdata[NTHR];

    const int s    = blockIdx.x >> 3;
    const int base = (blockIdx.x & 7) << 6;
    const int R0   = base - HALO;
    const int tid  = threadIdx.x;

    for (int i = tid; i < (NRTOT+2)*LP; i += NTHR) { A[i] = 0; B[i] = 0; }
    if (tid < 16) chg[tid] = 0;
    if (tid == 0) cflag = 0;
    __syncthreads();
    for (int i = tid; i < NRTOT*WPR; i += NTHR) {
        int lr = i >> 3, c = i & 7;
        int r = R0 + lr;
        if ((unsigned)r < (unsigned)HH)
            A[(lr+1)*LP + c + 1] = pack[((size_t)s*HH + r)*WPR + c];
    }
    __syncthreads();

    uint64_t* cur = A; uint64_t* nxt = B;
    int stable = 0;
    for (int step = 0; step < 16; ++step) {
        if (stable >= 2) break;                        // uniform across block
        const int lo = step + 1;                       // dependency cone: rows [lo, 105-step)
        const int nw = (NRTOT - 2 - 2*step) * WPR;
        bool mych = false;
        for (int i = tid; i < nw; i += NTHR) {
            int lr = (i >> 3) + lo, c = i & 7;
            int o = (lr+1)*LP + c + 1;
            uint64_t up = cur[o-LP-1], uc = cur[o-LP], un = cur[o-LP+1];
            uint64_t mp = cur[o-1],    mc = cur[o],    mn = cur[o+1];
            uint64_t dp = cur[o+LP-1], dc = cur[o+LP], dn = cur[o+LP+1];
            uint64_t p2 = uc;
            uint64_t p3 = (uc>>1)|(un<<63);
            uint64_t p4 = (mc>>1)|(mn<<63);
            uint64_t p5 = (dc>>1)|(dn<<63);
            uint64_t p6 = dc;
            uint64_t p7 = (dc<<1)|(dp>>63);
            uint64_t p8 = (mc<<1)|(mp>>63);
            uint64_t p9 = (uc<<1)|(up>>63);
            uint64_t qq[8] = {p2,p3,p4,p5,p6,p7,p8,p9};
            uint64_t n0,n1,n2,n3; sum8(qq,n0,n1,n2,n3);
            uint64_t condB = (n1|n2|n3) & ~(n3 | (n2&n1&n0));
            uint64_t tq[8];
            #pragma unroll
            for (int k = 0; k < 8; ++k) tq[k] = ~qq[k] & qq[(k+1)&7];
            uint64_t t0,t1,t2,t3; sum8(tq,t0,t1,t2,t3);
            uint64_t trans1 = t0 & ~(t1|t2|t3);
            uint64_t cond2 = (step & 1) ? (~(p2&p4&p8) & ~(p2&p6&p8))
                                        : (~(p2&p4&p6) & ~(p4&p6&p8));
            uint64_t nv = mc & ~(condB & trans1 & cond2);
            nxt[o] = nv;
            mych |= (nv != mc);
        }
        if (mych) chg[step] = 1;
        __syncthreads();
        stable = chg[step] ? 0 : stable + 1;
        uint64_t* t = cur; cur = nxt; nxt = t;
    }

    // Endpoint C (all 8 neighbors set) from skeleton (cur) into Cb (nxt),
    // rows lr 17..88.
    uint64_t* Cb = nxt;
    for (int i = tid; i < 72*WPR; i += NTHR) {
        int lr = (i >> 3) + 17, c = i & 7;
        int o = (lr+1)*LP + c + 1;
        uint64_t up = cur[o-LP-1], uc = cur[o-LP], un = cur[o-LP+1];
        uint64_t mp = cur[o-1],    mc = cur[o],    mn = cur[o+1];
        uint64_t dp = cur[o+LP-1], dc = cur[o+LP], dn = cur[o+LP+1];
        uint64_t p3 = (uc>>1)|(un<<63);
        uint64_t p4 = (mc>>1)|(mn<<63);
        uint64_t p5 = (dc>>1)|(dn<<63);
        uint64_t p7 = (dc<<1)|(dp>>63);
        uint64_t p8 = (mc<<1)|(mp>>63);
        uint64_t p9 = (uc<<1)|(up>>63);
        uint64_t cv = uc & p3 & p4 & p5 & dc & p7 & p8 & p9;
        Cb[o] = cv;
        if (cv) cflag = 1;
    }
    __syncthreads();

    if (!cflag) {                                      // uniform: weight map is 0
        if (tid == 0) partials[blockIdx.x] = 0.0;
        return;
    }

    // Phase A: horizontal 9-window sums (center included) -> 4 bit-planes
    for (int i = tid; i < 72*WPR; i += NTHR) {
        int hr = i >> 3, c = i & 7;
        int o = (hr+18)*LP + c + 1;                    // lr = hr+17
        uint64_t mp = Cb[o-1], mc = Cb[o], mn = Cb[o+1];
        uint64_t m[8];
        m[0] = (mc>>1)|(mn<<63); m[1] = (mc>>2)|(mn<<62);
        m[2] = (mc>>3)|(mn<<61); m[3] = (mc>>4)|(mn<<60);
        m[4] = (mc<<1)|(mp>>63); m[5] = (mc<<2)|(mp>>62);
        m[6] = (mc<<3)|(mp>>61); m[7] = (mc<<4)|(mp>>60);
        uint64_t b0,b1,b2,b3; sum8(m,b0,b1,b2,b3);
        uint64_t inc = mc;
        uint64_t s0 = b0 ^ inc; inc &= b0;
        uint64_t s1 = b1 ^ inc; inc &= b1;
        uint64_t s2 = b2 ^ inc; inc &= b2;
        uint64_t s3 = b3 ^ inc;
        Hs[0*576 + i] = s0; Hs[1*576 + i] = s1;
        Hs[2*576 + i] = s2; Hs[3*576 + i] = s3;
    }
    __syncthreads();

    // Phase B: vertical 9-row sums -> 7-bit weight, minus center C bit,
    // then sparse loss evaluation. (OUTR*WPR == 512 == NTHR: one word/thread)
    double acc = 0.0;
    for (int i = tid; i < OUTR*WPR; i += NTHR) {
        int orr = i >> 3, c = i & 7;
        uint64_t w[7];
        int h0 = orr*WPR + c;
        w[0] = Hs[0*576 + h0]; w[1] = Hs[1*576 + h0];
        w[2] = Hs[2*576 + h0]; w[3] = Hs[3*576 + h0];
        w[4] = 0; w[5] = 0; w[6] = 0;
        #pragma unroll
        for (int d = 1; d < 9; ++d) {
            int hh = (orr+d)*WPR + c;
            acc74(w, Hs[0*576+hh], Hs[1*576+hh], Hs[2*576+hh], Hs[3*576+hh]);
        }
        uint64_t cb = Cb[(orr+HALO+1)*LP + c + 1];
        #pragma unroll
        for (int j = 0; j < 7; ++j) {
            uint64_t t = w[j];
            w[j] = t ^ cb;
            cb &= ~t;
        }
        uint64_t any = w[0]|w[1]|w[2]|w[3]|w[4]|w[5]|w[6];
        if (any) {
            size_t pix0 = ((size_t)s*HH + (base + orr))*WW + ((size_t)c << 6);
            uint64_t rem = any;
            while (rem) {
                int bit = __builtin_ctzll(rem);
                rem &= rem - 1;
                int wv = 0;
                #pragma unroll
                for (int j = 0; j < 7; ++j) wv |= (int)((w[j] >> bit) & 1ULL) << j;
                size_t idx = pix0 + bit;
                float lx = x[idx], ly = y[idx];
                float loss = fmaxf(lx, 0.f) - lx*ly + log1pf(expf(-fabsf(lx)));
                acc += (double)(loss * (60.0f * (float)wv));
            }
        }
    }
    sdata[tid] = acc;
    __syncthreads();
    for (int s2 = NTHR/2; s2 > 0; s2 >>= 1) {
        if (tid < s2) sdata[tid] += sdata[tid + s2];
        __syncthreads();
    }
    if (tid == 0) partials[blockIdx.x] = sdata[0];
}

__global__ void k_reduce(const double* __restrict__ partials, float* __restrict__ out,
                         int nparts) {
    __shared__ double sdata[256];
    double a = 0.0;
    for (int i = threadIdx.x; i < nparts; i += 256) a += partials[i];
    sdata[threadIdx.x] = a;
    __syncthreads();
    for (int s2 = 128; s2 > 0; s2 >>= 1) {
        if (threadIdx.x < s2) sdata[threadIdx.x] += sdata[threadIdx.x + s2];
        __syncthreads();
    }
    if (threadIdx.x == 0) out[0] = (float)(sdata[0] / (double)NELEM);
}

// ---- launch ------------------------------------------------------------------

extern "C" void kernel_launch(void* const* d_in, const int* in_sizes, int n_in,
                              void* d_out, int out_size, void* d_ws, size_t ws_size,
                              hipStream_t stream) {
    const float* x = (const float*)d_in[0];
    const float* y = (const float*)d_in[1];
    char* ws = (char*)d_ws;
    double*   partials = (double*)(ws);                 // 4 KB
    uint64_t* packA    = (uint64_t*)(ws + 16384);       // 2 MB

    k_binarize<<<1024, 256, 0, stream>>>(x, packA);
    k_thin_wmap<<<NBLK, NTHR, 0, stream>>>(packA, x, y, partials);
    k_reduce<<<1, 256, 0, stream>>>(partials, (float*)d_out, NBLK);
}

// Round 8
// 27.901 us; speedup vs baseline: 2.0024x; 1.0663x over previous
//
#include <hip/hip_runtime.h>
#include <cstdint>

#define HH 512
#define WW 512
#define NBATCH 16
#define NPRED 4
#define WPR 8                        // 64-bit words per row
#define NELEM (NBATCH*NPRED*HH*WW)   // 16,777,216
#define HALO 21
#define OUTR 64                      // output rows per block
#define NRTOT (OUTR + 2*HALO)        // 106 LDS data rows
#define LP 10                        // LDS row stride; data in cols 2..9, cols 0-1 zero pad
#define NBLK 512                     // 64 slices * 8 blocks
#define NTHR 512

typedef float f4 __attribute__((ext_vector_type(4)));

// ---- bit-sliced helpers -----------------------------------------------------

static __device__ __forceinline__ void fadd(uint64_t a, uint64_t b, uint64_t ci,
                                            uint64_t& s, uint64_t& co) {
    uint64_t x = a ^ b;
    s  = x ^ ci;
    co = (a & b) | (ci & x);
}

static __device__ __forceinline__ void faddio(uint64_t& a, uint64_t b, uint64_t& c) {
    uint64_t x = a ^ b;
    uint64_t s = x ^ c;
    c = (a & b) | (c & x);
    a = s;
}

static __device__ __forceinline__ void sum8(const uint64_t q[8],
                                            uint64_t& b0, uint64_t& b1,
                                            uint64_t& b2, uint64_t& b3) {
    uint64_t s0,c0,s1,c1,s2,c2;
    fadd(q[0],q[1],q[2], s0,c0);
    fadd(q[3],q[4],q[5], s1,c1);
    s2 = q[6] ^ q[7]; c2 = q[6] & q[7];
    uint64_t ca; fadd(s0,s1,s2, b0, ca);
    uint64_t t, cb; fadd(c0,c1,c2, t, cb);
    b1 = t ^ ca; uint64_t cc = t & ca;
    b2 = cb ^ cc; b3 = cb & cc;
}

// w[0..6] += 4-bit number (b0..b3); max 81, no overflow past bit 6
static __device__ __forceinline__ void acc74(uint64_t w[7], uint64_t b0, uint64_t b1,
                                             uint64_t b2, uint64_t b3) {
    uint64_t c;
    { uint64_t x = w[0] ^ b0; c = w[0] & b0; w[0] = x; }
    faddio(w[1], b1, c);
    faddio(w[2], b2, c);
    faddio(w[3], b3, c);
    { uint64_t x = w[4] ^ c; c = w[4] & c; w[4] = x; }
    { uint64_t x = w[5] ^ c; c = w[5] & c; w[5] = x; }
    w[6] ^= c;
}

// Zhang-Suen delete mask for one word given its 8 shifted neighbor planes
static __device__ __forceinline__ uint64_t zs_word(uint64_t p2, uint64_t p3, uint64_t p4,
                                                   uint64_t p5, uint64_t p6, uint64_t p7,
                                                   uint64_t p8, uint64_t p9, int step) {
    uint64_t qq[8] = {p2,p3,p4,p5,p6,p7,p8,p9};
    uint64_t n0,n1,n2,n3; sum8(qq,n0,n1,n2,n3);
    uint64_t condB = (n1|n2|n3) & ~(n3 | (n2&n1&n0));
    uint64_t tq[8];
    #pragma unroll
    for (int k = 0; k < 8; ++k) tq[k] = ~qq[k] & qq[(k+1)&7];
    uint64_t t0,t1,t2,t3; sum8(tq,t0,t1,t2,t3);
    uint64_t trans1 = t0 & ~(t1|t2|t3);
    uint64_t cond2 = (step & 1) ? (~(p2&p4&p8) & ~(p2&p6&p8))
                                : (~(p2&p4&p6) & ~(p4&p6&p8));
    return condB & trans1 & cond2;
}

// ---- kernels ----------------------------------------------------------------

// softmax over batch axis (float4 nontemporal loads), threshold 0.5, pack bits.
__global__ __launch_bounds__(256) void k_binarize(const float* __restrict__ x,
                                                  uint64_t* __restrict__ pack) {
    __shared__ uint64_t nibs[272];                        // 256 + per-16 pad
    const int t = blockIdx.x * 256 + threadIdx.x;         // float4 index in (p,h,w)
    const f4* __restrict__ xv = reinterpret_cast<const f4*>(x);
    f4 va[NBATCH];
    #pragma unroll
    for (int b = 0; b < NBATCH; ++b)
        va[b] = __builtin_nontemporal_load(xv + (size_t)b * (NPRED*HH*WW/4) + t);
    f4 mx = va[0];
    #pragma unroll
    for (int b = 1; b < NBATCH; ++b) {
        mx.x = fmaxf(mx.x, va[b].x); mx.y = fmaxf(mx.y, va[b].y);
        mx.z = fmaxf(mx.z, va[b].z); mx.w = fmaxf(mx.w, va[b].w);
    }
    float sx=0.f, sy=0.f, sz=0.f, sw=0.f;
    #pragma unroll
    for (int b = 0; b < NBATCH; ++b) {
        sx += __expf(va[b].x - mx.x); sy += __expf(va[b].y - mx.y);
        sz += __expf(va[b].z - mx.z); sw += __expf(va[b].w - mx.w);
    }
    const float tx = mx.x + __logf(0.5f*sx), ty = mx.y + __logf(0.5f*sy);
    const float tz = mx.z + __logf(0.5f*sz), tw = mx.w + __logf(0.5f*sw);
    uint64_t nib = 0;
    #pragma unroll
    for (int b = 0; b < NBATCH; ++b) {
        unsigned n = (va[b].x >= tx ? 1u:0u) | (va[b].y >= ty ? 2u:0u)
                   | (va[b].z >= tz ? 4u:0u) | (va[b].w >= tw ? 8u:0u);
        nib |= (uint64_t)n << (4*b);
    }
    nibs[threadIdx.x + (threadIdx.x >> 4)] = nib;
    __syncthreads();
    // assemble one 64-px word per (wg,b) pair
    const int wg = threadIdx.x >> 4, b = threadIdx.x & 15;
    uint64_t word = 0;
    #pragma unroll
    for (int j = 0; j < 16; ++j)
        word |= ((nibs[wg*17 + j] >> (4*b)) & 0xFULL) << (4*j);
    const int wgg = blockIdx.x * 16 + wg;                 // global word index
    const int wword = wgg & 7;
    const int h = (wgg >> 3) & (HH-1);
    const int p = wgg >> 12;
    pack[((size_t)(b*NPRED + p)*HH + h)*WPR + wword] = word;
}

// fused: 16 Zhang-Suen substeps (cone-shrunk, pair-processed, early-exit) +
// endpoint C + 9x9-minus-center weight + sparse loss eval -> per-block partial.
// LDS layout: data word c of row lr lives at (lr+1)*LP + c + 2; cols 0,1 are
// permanent zero pads (right-neighbor of word 7 reads next row's col 0 == 0).
__global__ __launch_bounds__(NTHR) void k_thin_wmap(const uint64_t* __restrict__ pack,
                                                    const float* __restrict__ x,
                                                    const float* __restrict__ y,
                                                    double* __restrict__ partials) {
    __shared__ uint64_t A[(NRTOT+2)*LP + 2];
    __shared__ uint64_t B[(NRTOT+2)*LP + 2];
    __shared__ uint64_t Hs[4*72*WPR];                  // horizontal-sum planes
    __shared__ int chg[16];
    __shared__ int cflag;
    __shared__ double sdata[NTHR];

    const int s    = blockIdx.x >> 3;
    const int base = (blockIdx.x & 7) << 6;
    const int R0   = base - HALO;
    const int tid  = threadIdx.x;

    for (int i = tid; i < (NRTOT+2)*LP + 2; i += NTHR) { A[i] = 0; B[i] = 0; }
    if (tid < 16) chg[tid] = 0;
    if (tid == 0) cflag = 0;
    __syncthreads();
    for (int i = tid; i < NRTOT*WPR; i += NTHR) {
        int lr = i >> 3, c = i & 7;
        int r = R0 + lr;
        if ((unsigned)r < (unsigned)HH)
            A[(lr+1)*LP + c + 2] = pack[((size_t)s*HH + r)*WPR + c];
    }
    __syncthreads();

    uint64_t* cur = A; uint64_t* nxt = B;
    int stable = 0;
    for (int step = 0; step < 16; ++step) {
        if (stable >= 2) break;                        // uniform across block
        const int lo = step + 1;                       // cone: rows [lo, 105-step)
        const int np = (NRTOT - 2 - 2*step) * 4;       // pair-tasks this step
        bool mych = false;
        for (int i = tid; i < np; i += NTHR) {
            const int lr = (i >> 2) + lo;
            const int c0 = (i & 3) << 1;               // word pair (c0, c0+1)
            const int o  = (lr+1)*LP + c0 + 2;         // 16B-aligned (even)
            // 3 rows x {b64 left, b128 center-pair, b64 right}
            uint64_t ul = cur[o-LP-1];
            ulonglong2 uc2 = *reinterpret_cast<const ulonglong2*>(&cur[o-LP]);
            uint64_t ur = cur[o-LP+2];
            uint64_t ml = cur[o-1];
            ulonglong2 mc2 = *reinterpret_cast<const ulonglong2*>(&cur[o]);
            uint64_t mr = cur[o+2];
            uint64_t dl = cur[o+LP-1];
            ulonglong2 dc2 = *reinterpret_cast<const ulonglong2*>(&cur[o+LP]);
            uint64_t dr = cur[o+LP+2];

            // word 0 of pair
            uint64_t w0 = mc2.x, w1 = mc2.y;
            uint64_t d0, d1;
            {
                uint64_t p2 = uc2.x;
                uint64_t p3 = (uc2.x>>1)|(uc2.y<<63);
                uint64_t p4 = (w0>>1)|(w1<<63);
                uint64_t p5 = (dc2.x>>1)|(dc2.y<<63);
                uint64_t p6 = dc2.x;
                uint64_t p7 = (dc2.x<<1)|(dl>>63);
                uint64_t p8 = (w0<<1)|(ml>>63);
                uint64_t p9 = (uc2.x<<1)|(ul>>63);
                d0 = zs_word(p2,p3,p4,p5,p6,p7,p8,p9, step);
            }
            // word 1 of pair
            {
                uint64_t p2 = uc2.y;
                uint64_t p3 = (uc2.y>>1)|(ur<<63);
                uint64_t p4 = (w1>>1)|(mr<<63);
                uint64_t p5 = (dc2.y>>1)|(dr<<63);
                uint64_t p6 = dc2.y;
                uint64_t p7 = (dc2.y<<1)|(dc2.x>>63);
                uint64_t p8 = (w1<<1)|(w0>>63);
                uint64_t p9 = (uc2.y<<1)|(uc2.x>>63);
                d1 = zs_word(p2,p3,p4,p5,p6,p7,p8,p9, step);
            }
            ulonglong2 nv;
            nv.x = w0 & ~d0;
            nv.y = w1 & ~d1;
            *reinterpret_cast<ulonglong2*>(&nxt[o]) = nv;
            mych |= (nv.x != w0) | (nv.y != w1);
        }
        if (mych) chg[step] = 1;
        __syncthreads();
        stable = chg[step] ? 0 : stable + 1;
        uint64_t* t = cur; cur = nxt; nxt = t;
    }

    // Endpoint C (all 8 neighbors set) from skeleton (cur) into Cb (nxt),
    // rows lr 17..88.
    uint64_t* Cb = nxt;
    for (int i = tid; i < 72*WPR; i += NTHR) {
        int lr = (i >> 3) + 17, c = i & 7;
        int o = (lr+1)*LP + c + 2;
        uint64_t up = cur[o-LP-1], uc = cur[o-LP], un = cur[o-LP+1];
        uint64_t mp = cur[o-1],    mc = cur[o],    mn = cur[o+1];
        uint64_t dp = cur[o+LP-1], dc = cur[o+LP], dn = cur[o+LP+1];
        uint64_t p3 = (uc>>1)|(un<<63);
        uint64_t p4 = (mc>>1)|(mn<<63);
        uint64_t p5 = (dc>>1)|(dn<<63);
        uint64_t p7 = (dc<<1)|(dp>>63);
        uint64_t p8 = (mc<<1)|(mp>>63);
        uint64_t p9 = (uc<<1)|(up>>63);
        uint64_t cv = uc & p3 & p4 & p5 & dc & p7 & p8 & p9;
        Cb[o] = cv;
        if (cv) cflag = 1;
    }
    __syncthreads();

    if (!cflag) {                                      // uniform: weight map is 0
        if (tid == 0) partials[blockIdx.x] = 0.0;
        return;
    }

    // Phase A: horizontal 9-window sums (center included) -> 4 bit-planes
    for (int i = tid; i < 72*WPR; i += NTHR) {
        int hr = i >> 3, c = i & 7;
        int o = (hr+18)*LP + c + 2;                    // lr = hr+17
        uint64_t mp = Cb[o-1], mc = Cb[o], mn = Cb[o+1];
        uint64_t m[8];
        m[0] = (mc>>1)|(mn<<63); m[1] = (mc>>2)|(mn<<62);
        m[2] = (mc>>3)|(mn<<61); m[3] = (mc>>4)|(mn<<60);
        m[4] = (mc<<1)|(mp>>63); m[5] = (mc<<2)|(mp>>62);
        m[6] = (mc<<3)|(mp>>61); m[7] = (mc<<4)|(mp>>60);
        uint64_t b0,b1,b2,b3; sum8(m,b0,b1,b2,b3);
        uint64_t inc = mc;
        uint64_t s0 = b0 ^ inc; inc &= b0;
        uint64_t s1 = b1 ^ inc; inc &= b1;
        uint64_t s2 = b2 ^ inc; inc &= b2;
        uint64_t s3 = b3 ^ inc;
        Hs[0*576 + i] = s0; Hs[1*576 + i] = s1;
        Hs[2*576 + i] = s2; Hs[3*576 + i] = s3;
    }
    __syncthreads();

    // Phase B: vertical 9-row sums -> 7-bit weight, minus center C bit,
    // then sparse loss evaluation. (OUTR*WPR == 512 == NTHR)
    double acc = 0.0;
    for (int i = tid; i < OUTR*WPR; i += NTHR) {
        int orr = i >> 3, c = i & 7;
        uint64_t w[7];
        int h0 = orr*WPR + c;
        w[0] = Hs[0*576 + h0]; w[1] = Hs[1*576 + h0];
        w[2] = Hs[2*576 + h0]; w[3] = Hs[3*576 + h0];
        w[4] = 0; w[5] = 0; w[6] = 0;
        #pragma unroll
        for (int d = 1; d < 9; ++d) {
            int hh = (orr+d)*WPR + c;
            acc74(w, Hs[0*576+hh], Hs[1*576+hh], Hs[2*576+hh], Hs[3*576+hh]);
        }
        uint64_t cb = Cb[(orr+HALO+1)*LP + c + 2];
        #pragma unroll
        for (int j = 0; j < 7; ++j) {
            uint64_t t = w[j];
            w[j] = t ^ cb;
            cb &= ~t;
        }
        uint64_t any = w[0]|w[1]|w[2]|w[3]|w[4]|w[5]|w[6];
        if (any) {
            size_t pix0 = ((size_t)s*HH + (base + orr))*WW + ((size_t)c << 6);
            uint64_t rem = any;
            while (rem) {
                int bit = __builtin_ctzll(rem);
                rem &= rem - 1;
                int wv = 0;
                #pragma unroll
                for (int j = 0; j < 7; ++j) wv |= (int)((w[j] >> bit) & 1ULL) << j;
                size_t idx = pix0 + bit;
                float lx = x[idx], ly = y[idx];
                float loss = fmaxf(lx, 0.f) - lx*ly + log1pf(expf(-fabsf(lx)));
                acc += (double)(loss * (60.0f * (float)wv));
            }
        }
    }
    sdata[tid] = acc;
    __syncthreads();
    for (int s2 = NTHR/2; s2 > 0; s2 >>= 1) {
        if (tid < s2) sdata[tid] += sdata[tid + s2];
        __syncthreads();
    }
    if (tid == 0) partials[blockIdx.x] = sdata[0];
}

__global__ void k_reduce(const double* __restrict__ partials, float* __restrict__ out,
                         int nparts) {
    __shared__ double sdata[256];
    double a = 0.0;
    for (int i = threadIdx.x; i < nparts; i += 256) a += partials[i];
    sdata[threadIdx.x] = a;
    __syncthreads();
    for (int s2 = 128; s2 > 0; s2 >>= 1) {
        if (threadIdx.x < s2) sdata[threadIdx.x] += sdata[threadIdx.x + s2];
        __syncthreads();
    }
    if (threadIdx.x == 0) out[0] = (float)(sdata[0] / (double)NELEM);
}

// ---- launch ------------------------------------------------------------------

extern "C" void kernel_launch(void* const* d_in, const int* in_sizes, int n_in,
                              void* d_out, int out_size, void* d_ws, size_t ws_size,
                              hipStream_t stream) {
    const float* x = (const float*)d_in[0];
    const float* y = (const float*)d_in[1];
    char* ws = (char*)d_ws;
    double*   partials = (double*)(ws);                 // 4 KB
    uint64_t* packA    = (uint64_t*)(ws + 16384);       // 2 MB

    k_binarize<<<1024, 256, 0, stream>>>(x, packA);
    k_thin_wmap<<<NBLK, NTHR, 0, stream>>>(packA, x, y, partials);
    k_reduce<<<1, 256, 0, stream>>>(partials, (float*)d_out, NBLK);
}

// Round 9
// 25.710 us; speedup vs baseline: 2.1730x; 1.0852x over previous
//
#include <hip/hip_runtime.h>
#include <cstdint>

#define HH 512
#define WW 512
#define NBATCH 16
#define NPRED 4
#define WPR 8                        // 64-bit words per row
#define NELEM (NBATCH*NPRED*HH*WW)   // 16,777,216
#define HALO 21
#define OUTR 64                      // output rows per block
#define NRTOT (OUTR + 2*HALO)        // 106 LDS data rows
#define LP 10                        // LDS row stride; data cols 2..9, cols 0-1 zero pad
#define NBLK 512                     // 64 slices * 8 blocks
#define NTHR 512

typedef float f4 __attribute__((ext_vector_type(4)));

// ---- bit-sliced helpers -----------------------------------------------------

static __device__ __forceinline__ void fadd(uint64_t a, uint64_t b, uint64_t ci,
                                            uint64_t& s, uint64_t& co) {
    uint64_t x = a ^ b;
    s  = x ^ ci;
    co = (a & b) | (ci & x);
}

static __device__ __forceinline__ void faddio(uint64_t& a, uint64_t b, uint64_t& c) {
    uint64_t x = a ^ b;
    uint64_t s = x ^ c;
    c = (a & b) | (c & x);
    a = s;
}

static __device__ __forceinline__ void sum8(const uint64_t q[8],
                                            uint64_t& b0, uint64_t& b1,
                                            uint64_t& b2, uint64_t& b3) {
    uint64_t s0,c0,s1,c1,s2,c2;
    fadd(q[0],q[1],q[2], s0,c0);
    fadd(q[3],q[4],q[5], s1,c1);
    s2 = q[6] ^ q[7]; c2 = q[6] & q[7];
    uint64_t ca; fadd(s0,s1,s2, b0, ca);
    uint64_t t, cb; fadd(c0,c1,c2, t, cb);
    b1 = t ^ ca; uint64_t cc = t & ca;
    b2 = cb ^ cc; b3 = cb & cc;
}

// w[0..6] += 4-bit number (b0..b3); max 81, no overflow past bit 6
static __device__ __forceinline__ void acc74(uint64_t w[7], uint64_t b0, uint64_t b1,
                                             uint64_t b2, uint64_t b3) {
    uint64_t c;
    { uint64_t x = w[0] ^ b0; c = w[0] & b0; w[0] = x; }
    faddio(w[1], b1, c);
    faddio(w[2], b2, c);
    faddio(w[3], b3, c);
    { uint64_t x = w[4] ^ c; c = w[4] & c; w[4] = x; }
    { uint64_t x = w[5] ^ c; c = w[5] & c; w[5] = x; }
    w[6] ^= c;
}

// Zhang-Suen delete mask for one word given its 8 shifted neighbor planes
static __device__ __forceinline__ uint64_t zs_word(uint64_t p2, uint64_t p3, uint64_t p4,
                                                   uint64_t p5, uint64_t p6, uint64_t p7,
                                                   uint64_t p8, uint64_t p9, int step) {
    uint64_t qq[8] = {p2,p3,p4,p5,p6,p7,p8,p9};
    uint64_t n0,n1,n2,n3; sum8(qq,n0,n1,n2,n3);
    uint64_t condB = (n1|n2|n3) & ~(n3 | (n2&n1&n0));
    uint64_t tq[8];
    #pragma unroll
    for (int k = 0; k < 8; ++k) tq[k] = ~qq[k] & qq[(k+1)&7];
    uint64_t t0,t1,t2,t3; sum8(tq,t0,t1,t2,t3);
    uint64_t trans1 = t0 & ~(t1|t2|t3);
    uint64_t cond2 = (step & 1) ? (~(p2&p4&p8) & ~(p2&p6&p8))
                                : (~(p2&p4&p6) & ~(p4&p6&p8));
    return condB & trans1 & cond2;
}

// ---- kernels ----------------------------------------------------------------

// softmax over batch axis (float4 nontemporal loads), threshold 0.5, pack bits.
__global__ __launch_bounds__(256) void k_binarize(const float* __restrict__ x,
                                                  uint64_t* __restrict__ pack) {
    __shared__ uint64_t nibs[272];                        // 256 + per-16 pad
    const int t = blockIdx.x * 256 + threadIdx.x;         // float4 index in (p,h,w)
    const f4* __restrict__ xv = reinterpret_cast<const f4*>(x);
    f4 va[NBATCH];
    #pragma unroll
    for (int b = 0; b < NBATCH; ++b)
        va[b] = __builtin_nontemporal_load(xv + (size_t)b * (NPRED*HH*WW/4) + t);
    f4 mx = va[0];
    #pragma unroll
    for (int b = 1; b < NBATCH; ++b) {
        mx.x = fmaxf(mx.x, va[b].x); mx.y = fmaxf(mx.y, va[b].y);
        mx.z = fmaxf(mx.z, va[b].z); mx.w = fmaxf(mx.w, va[b].w);
    }
    float sx=0.f, sy=0.f, sz=0.f, sw=0.f;
    #pragma unroll
    for (int b = 0; b < NBATCH; ++b) {
        sx += __expf(va[b].x - mx.x); sy += __expf(va[b].y - mx.y);
        sz += __expf(va[b].z - mx.z); sw += __expf(va[b].w - mx.w);
    }
    const float tx = mx.x + __logf(0.5f*sx), ty = mx.y + __logf(0.5f*sy);
    const float tz = mx.z + __logf(0.5f*sz), tw = mx.w + __logf(0.5f*sw);
    uint64_t nib = 0;
    #pragma unroll
    for (int b = 0; b < NBATCH; ++b) {
        unsigned n = (va[b].x >= tx ? 1u:0u) | (va[b].y >= ty ? 2u:0u)
                   | (va[b].z >= tz ? 4u:0u) | (va[b].w >= tw ? 8u:0u);
        nib |= (uint64_t)n << (4*b);
    }
    nibs[threadIdx.x + (threadIdx.x >> 4)] = nib;
    __syncthreads();
    // assemble one 64-px word per (wg,b) pair
    const int wg = threadIdx.x >> 4, b = threadIdx.x & 15;
    uint64_t word = 0;
    #pragma unroll
    for (int j = 0; j < 16; ++j)
        word |= ((nibs[wg*17 + j] >> (4*b)) & 0xFULL) << (4*j);
    const int wgg = blockIdx.x * 16 + wg;                 // global word index
    const int wword = wgg & 7;
    const int h = (wgg >> 3) & (HH-1);
    const int p = wgg >> 12;
    pack[((size_t)(b*NPRED + p)*HH + h)*WPR + wword] = word;
}

// fused: 16 Zhang-Suen substeps (cone-shrunk, pair-processed, row-activity
// tracked, early-exit) + endpoint C + 9x9-minus-center weight + sparse loss
// eval -> per-block double partial.
__global__ __launch_bounds__(NTHR) void k_thin_wmap(const uint64_t* __restrict__ pack,
                                                    const float* __restrict__ x,
                                                    const float* __restrict__ y,
                                                    double* __restrict__ partials) {
    __shared__ uint64_t A[(NRTOT+2)*LP + 2];
    __shared__ uint64_t B[(NRTOT+2)*LP + 2];
    __shared__ uint64_t Hs[4*72*WPR];                  // horizontal-sum planes
    __shared__ int rc[NRTOT+2];                        // row last-changed step (+1)
    __shared__ int chg[16];
    __shared__ int cflag;
    __shared__ double sdata[NTHR];

    const int s    = blockIdx.x >> 3;
    const int base = (blockIdx.x & 7) << 6;
    const int R0   = base - HALO;
    const int tid  = threadIdx.x;

    for (int i = tid; i < (NRTOT+2)*LP + 2; i += NTHR) { A[i] = 0; B[i] = 0; }
    for (int i = tid; i < NRTOT+2; i += NTHR) rc[i] = 0;   // all rows active at step 0
    if (tid < 16) chg[tid] = 0;
    if (tid == 0) cflag = 0;
    __syncthreads();
    for (int i = tid; i < NRTOT*WPR; i += NTHR) {
        int lr = i >> 3, c = i & 7;
        int r = R0 + lr;
        if ((unsigned)r < (unsigned)HH)
            A[(lr+1)*LP + c + 2] = pack[((size_t)s*HH + r)*WPR + c];
    }
    __syncthreads();

    uint64_t* cur = A; uint64_t* nxt = B;
    int stable = 0;
    for (int step = 0; step < 16; ++step) {
        if (stable >= 2) break;                        // fixpoint (both parities quiet)
        const int lo = step + 1;                       // cone: rows [lo, 105-step)
        const int np = (NRTOT - 2 - 2*step) * 4;       // pair-tasks this step
        bool mych = false;
        for (int i = tid; i < np; i += NTHR) {
            const int lr = (i >> 2) + lo;
            const int c0 = (i & 3) << 1;               // word pair (c0, c0+1)
            const int o  = (lr+1)*LP + c0 + 2;         // 16B-aligned (even)
            // activity: inputs changed last step? (race-conservative: a concurrent
            // write of step+1 only widens the active set)
            const bool act = (rc[lr-1] >= step) | (rc[lr] >= step) | (rc[lr+1] >= step);
            if (act) {
                uint64_t ul = cur[o-LP-1];
                ulonglong2 uc2 = *reinterpret_cast<const ulonglong2*>(&cur[o-LP]);
                uint64_t ur = cur[o-LP+2];
                uint64_t ml = cur[o-1];
                ulonglong2 mc2 = *reinterpret_cast<const ulonglong2*>(&cur[o]);
                uint64_t mr = cur[o+2];
                uint64_t dl = cur[o+LP-1];
                ulonglong2 dc2 = *reinterpret_cast<const ulonglong2*>(&cur[o+LP]);
                uint64_t dr = cur[o+LP+2];
                uint64_t w0 = mc2.x, w1 = mc2.y;
                uint64_t d0, d1;
                {
                    uint64_t p2 = uc2.x;
                    uint64_t p3 = (uc2.x>>1)|(uc2.y<<63);
                    uint64_t p4 = (w0>>1)|(w1<<63);
                    uint64_t p5 = (dc2.x>>1)|(dc2.y<<63);
                    uint64_t p6 = dc2.x;
                    uint64_t p7 = (dc2.x<<1)|(dl>>63);
                    uint64_t p8 = (w0<<1)|(ml>>63);
                    uint64_t p9 = (uc2.x<<1)|(ul>>63);
                    d0 = zs_word(p2,p3,p4,p5,p6,p7,p8,p9, step);
                }
                {
                    uint64_t p2 = uc2.y;
                    uint64_t p3 = (uc2.y>>1)|(ur<<63);
                    uint64_t p4 = (w1>>1)|(mr<<63);
                    uint64_t p5 = (dc2.y>>1)|(dr<<63);
                    uint64_t p6 = dc2.y;
                    uint64_t p7 = (dc2.y<<1)|(dc2.x>>63);
                    uint64_t p8 = (w1<<1)|(w0>>63);
                    uint64_t p9 = (uc2.y<<1)|(uc2.x>>63);
                    d1 = zs_word(p2,p3,p4,p5,p6,p7,p8,p9, step);
                }
                ulonglong2 nv;
                nv.x = w0 & ~d0;
                nv.y = w1 & ~d1;
                *reinterpret_cast<ulonglong2*>(&nxt[o]) = nv;
                if ((nv.x != w0) | (nv.y != w1)) { mych = true; rc[lr] = step + 1; }
            } else {
                // inputs unchanged -> output == current value: plain copy
                *reinterpret_cast<ulonglong2*>(&nxt[o]) =
                    *reinterpret_cast<const ulonglong2*>(&cur[o]);
            }
        }
        if (mych) chg[step] = 1;
        __syncthreads();
        stable = chg[step] ? 0 : stable + 1;
        uint64_t* t = cur; cur = nxt; nxt = t;
    }

    // Endpoint C (all 8 neighbors set) from skeleton (cur) into Cb (nxt),
    // rows lr 17..88.
    uint64_t* Cb = nxt;
    for (int i = tid; i < 72*WPR; i += NTHR) {
        int lr = (i >> 3) + 17, c = i & 7;
        int o = (lr+1)*LP + c + 2;
        uint64_t up = cur[o-LP-1], uc = cur[o-LP], un = cur[o-LP+1];
        uint64_t mp = cur[o-1],    mc = cur[o],    mn = cur[o+1];
        uint64_t dp = cur[o+LP-1], dc = cur[o+LP], dn = cur[o+LP+1];
        uint64_t p3 = (uc>>1)|(un<<63);
        uint64_t p4 = (mc>>1)|(mn<<63);
        uint64_t p5 = (dc>>1)|(dn<<63);
        uint64_t p7 = (dc<<1)|(dp>>63);
        uint64_t p8 = (mc<<1)|(mp>>63);
        uint64_t p9 = (uc<<1)|(up>>63);
        uint64_t cv = uc & p3 & p4 & p5 & dc & p7 & p8 & p9;
        Cb[o] = cv;
        if (cv) cflag = 1;
    }
    __syncthreads();

    if (!cflag) {                                      // weight map identically 0
        if (tid == 0) partials[blockIdx.x] = 0.0;
        return;
    }

    // Phase A: horizontal 9-window sums (center included) -> 4 bit-planes
    for (int i = tid; i < 72*WPR; i += NTHR) {
        int hr = i >> 3, c = i & 7;
        int o = (hr+18)*LP + c + 2;                    // lr = hr+17
        uint64_t mp = Cb[o-1], mc = Cb[o], mn = Cb[o+1];
        uint64_t m[8];
        m[0] = (mc>>1)|(mn<<63); m[1] = (mc>>2)|(mn<<62);
        m[2] = (mc>>3)|(mn<<61); m[3] = (mc>>4)|(mn<<60);
        m[4] = (mc<<1)|(mp>>63); m[5] = (mc<<2)|(mp>>62);
        m[6] = (mc<<3)|(mp>>61); m[7] = (mc<<4)|(mp>>60);
        uint64_t b0,b1,b2,b3; sum8(m,b0,b1,b2,b3);
        uint64_t inc = mc;
        uint64_t s0 = b0 ^ inc; inc &= b0;
        uint64_t s1 = b1 ^ inc; inc &= b1;
        uint64_t s2 = b2 ^ inc; inc &= b2;
        uint64_t s3 = b3 ^ inc;
        Hs[0*576 + i] = s0; Hs[1*576 + i] = s1;
        Hs[2*576 + i] = s2; Hs[3*576 + i] = s3;
    }
    __syncthreads();

    // Phase B: vertical 9-row sums -> 7-bit weight, minus center C bit,
    // then sparse loss evaluation. (OUTR*WPR == 512 == NTHR)
    double acc = 0.0;
    for (int i = tid; i < OUTR*WPR; i += NTHR) {
        int orr = i >> 3, c = i & 7;
        uint64_t w[7];
        int h0 = orr*WPR + c;
        w[0] = Hs[0*576 + h0]; w[1] = Hs[1*576 + h0];
        w[2] = Hs[2*576 + h0]; w[3] = Hs[3*576 + h0];
        w[4] = 0; w[5] = 0; w[6] = 0;
        #pragma unroll
        for (int d = 1; d < 9; ++d) {
            int hh = (orr+d)*WPR + c;
            acc74(w, Hs[0*576+hh], Hs[1*576+hh], Hs[2*576+hh], Hs[3*576+hh]);
        }
        uint64_t cb = Cb[(orr+HALO+1)*LP + c + 2];
        #pragma unroll
        for (int j = 0; j < 7; ++j) {
            uint64_t t = w[j];
            w[j] = t ^ cb;
            cb &= ~t;
        }
        uint64_t any = w[0]|w[1]|w[2]|w[3]|w[4]|w[5]|w[6];
        if (any) {
            size_t pix0 = ((size_t)s*HH + (base + orr))*WW + ((size_t)c << 6);
            uint64_t rem = any;
            while (rem) {
                int bit = __builtin_ctzll(rem);
                rem &= rem - 1;
                int wv = 0;
                #pragma unroll
                for (int j = 0; j < 7; ++j) wv |= (int)((w[j] >> bit) & 1ULL) << j;
                size_t idx = pix0 + bit;
                float lx = x[idx], ly = y[idx];
                float loss = fmaxf(lx, 0.f) - lx*ly + log1pf(expf(-fabsf(lx)));
                acc += (double)(loss * (60.0f * (float)wv));
            }
        }
    }
    sdata[tid] = acc;
    __syncthreads();
    for (int s2 = NTHR/2; s2 > 0; s2 >>= 1) {
        if (tid < s2) sdata[tid] += sdata[tid + s2];
        __syncthreads();
    }
    if (tid == 0) partials[blockIdx.x] = sdata[0];
}

__global__ __launch_bounds__(512) void k_reduce(const double* __restrict__ partials,
                                                float* __restrict__ out, int nparts) {
    __shared__ double sdata[512];
    double a = 0.0;
    for (int i = threadIdx.x; i < nparts; i += 512) a += partials[i];
    sdata[threadIdx.x] = a;
    __syncthreads();
    for (int s2 = 256; s2 > 0; s2 >>= 1) {
        if (threadIdx.x < s2) sdata[threadIdx.x] += sdata[threadIdx.x + s2];
        __syncthreads();
    }
    if (threadIdx.x == 0) out[0] = (float)(sdata[0] / (double)NELEM);
}

// ---- launch ------------------------------------------------------------------

extern "C" void kernel_launch(void* const* d_in, const int* in_sizes, int n_in,
                              void* d_out, int out_size, void* d_ws, size_t ws_size,
                              hipStream_t stream) {
    const float* x = (const float*)d_in[0];
    const float* y = (const float*)d_in[1];
    char* ws = (char*)d_ws;
    double*   partials = (double*)(ws);                 // 4 KB
    uint64_t* packA    = (uint64_t*)(ws + 16384);       // 2 MB

    k_binarize<<<1024, 256, 0, stream>>>(x, packA);
    k_thin_wmap<<<NBLK, NTHR, 0, stream>>>(packA, x, y, partials);
    k_reduce<<<1, 512, 0, stream>>>(partials, (float*)d_out, NBLK);
}